// Round 1
// baseline (295.375 us; speedup 1.0000x reference)
//
#include <hip/hip_runtime.h>
#include <math.h>

#define RES 256
#define PAD 258          // RES + 1-pixel zero border on each side
#define N_ANGLES 256
#define BATCH 8

// Build zero-padded image P[b][258][258] and its transpose PT[b][258][258].
// Pad means bilinear taps at row/col in [-1, RES) never need a bounds branch.
__global__ void prep_pad(const float* __restrict__ imgs,
                         float* __restrict__ P,
                         float* __restrict__ PT) {
    int idx = blockIdx.x * blockDim.x + threadIdx.x;
    const int total = BATCH * PAD * PAD;
    if (idx >= total) return;
    int c = idx % PAD;
    int r = (idx / PAD) % PAD;
    int b = idx / (PAD * PAD);
    float v = 0.0f;
    if (r >= 1 && r <= RES && c >= 1 && c <= RES)
        v = imgs[(b * RES + (r - 1)) * RES + (c - 1)];
    P[(b * PAD + r) * PAD + c] = v;
    PT[(b * PAD + c) * PAD + r] = v;
}

// One thread per (b, a, s); loop over ray steps t (clipped to image support).
// Padded coords: pr = y + 128.5, pc = x + 128.5, valid sampling range (0, 257).
__global__ __launch_bounds__(256) void radon_kernel(
        const float* __restrict__ P,
        const float* __restrict__ PT,
        const float* __restrict__ angles,
        float* __restrict__ out) {
    const int s = threadIdx.x;          // detector bin, lanes consecutive in s
    const int a = blockIdx.x;
    const int b = blockIdx.y;

    float theta = angles[a];
    float sn, cs;
    sincosf(theta, &sn, &cs);

    const float s_c = (float)s - 127.5f;

    // Choose layout so that per-lane (Δs) movement along the contiguous dim
    // (pc) has magnitude max(|cos|,|sin|) >= 0.707 -> bounded line fan-out.
    float Rs, Rt, Cs, Ct;
    const float* img;
    if (fabsf(cs) >= fabsf(sn)) {
        Rs = sn; Rt = cs;  Cs = cs; Ct = -sn;
        img = P + (size_t)b * PAD * PAD;
    } else {
        // sample transposed image: (pr', pc') = (pc, pr)
        Rs = cs; Rt = -sn; Cs = sn; Ct = cs;
        img = PT + (size_t)b * PAD * PAD;
    }

    // pr(t) = pr0 + t*Rt, pc(t) = pc0 + t*Ct, t = 0..255
    const float pr0 = fmaf(s_c, Rs, 128.5f) - 127.5f * Rt;
    const float pc0 = fmaf(s_c, Cs, 128.5f) - 127.5f * Ct;

    // Clip t so both padded coords stay in (0, 257): all 4 taps in-array,
    // anything trimmed has (near-)zero bilinear weight.
    const float LO = 1e-4f, HI = 257.0f - 1e-3f;
    float tmin = 0.0f, tmax = 255.0f;
    if (fabsf(Rt) > 1e-6f) {
        float ta = (LO - pr0) / Rt, tb = (HI - pr0) / Rt;
        tmin = fmaxf(tmin, fminf(ta, tb));
        tmax = fminf(tmax, fmaxf(ta, tb));
    } else if (!(pr0 >= LO && pr0 <= HI)) {
        tmax = -1.0f;
    }
    if (fabsf(Ct) > 1e-6f) {
        float ta = (LO - pc0) / Ct, tb = (HI - pc0) / Ct;
        tmin = fmaxf(tmin, fminf(ta, tb));
        tmax = fminf(tmax, fmaxf(ta, tb));
    } else if (!(pc0 >= LO && pc0 <= HI)) {
        tmax = -1.0f;
    }

    int t0 = (int)ceilf(tmin);
    int t1 = (int)floorf(tmax);

    float acc = 0.0f;
    float tf = (float)t0;
    for (int t = t0; t <= t1; ++t) {
        float pr = fmaf(tf, Rt, pr0);
        float pc = fmaf(tf, Ct, pc0);
        tf += 1.0f;
        float fr = floorf(pr), fc = floorf(pc);
        int ir = (int)fr, ic = (int)fc;
        float wy = pr - fr, wx = pc - fc;
        const float* p0 = img + ir * PAD + ic;
        float v00 = p0[0];
        float v01 = p0[1];
        float v10 = p0[PAD];
        float v11 = p0[PAD + 1];
        float top = fmaf(wx, v01 - v00, v00);
        float bot = fmaf(wx, v11 - v10, v10);
        acc += fmaf(wy, bot - top, top);
    }

    out[((size_t)b * N_ANGLES + a) * RES + s] = acc;
}

extern "C" void kernel_launch(void* const* d_in, const int* in_sizes, int n_in,
                              void* d_out, int out_size, void* d_ws, size_t ws_size,
                              hipStream_t stream) {
    const float* imgs   = (const float*)d_in[0];
    const float* angles = (const float*)d_in[1];
    float* out = (float*)d_out;

    float* P  = (float*)d_ws;                                   // 8*258*258 f32
    float* PT = P + (size_t)BATCH * PAD * PAD;                  // another 2.13MB

    const int prep_total = BATCH * PAD * PAD;
    prep_pad<<<(prep_total + 255) / 256, 256, 0, stream>>>(imgs, P, PT);

    dim3 grid(N_ANGLES, BATCH);
    radon_kernel<<<grid, 256, 0, stream>>>(P, PT, angles, out);
}

// Round 2
// 188.033 us; speedup vs baseline: 1.5709x; 1.5709x over previous
//
#include <hip/hip_runtime.h>
#include <hip/hip_fp16.h>
#include <math.h>

#define RES 256
#define PAD 258          // RES + 1-pixel zero border on each side
#define N_ANGLES 256
#define BATCH 8

// P(r,c) over the padded index space [0,258): zero border, else imgs[r-1][c-1]
__device__ inline float getP(const float* __restrict__ img, int r, int c) {
    unsigned rr = (unsigned)(r - 1), cc = (unsigned)(c - 1);
    return (rr < RES && cc < RES) ? img[rr * RES + cc] : 0.0f;
}

// Packed tap texture: Q[b][r][c] = half4{ P(r,c), P(r+1,c), P(r,c+1), P(r+1,c+1) }
// -> one 8B load yields all 4 bilinear taps. QT is the transposed-image version.
__global__ void prep_pack(const float* __restrict__ imgs,
                          uint2* __restrict__ Q,
                          uint2* __restrict__ QT) {
    int idx = blockIdx.x * blockDim.x + threadIdx.x;
    const int total = BATCH * PAD * PAD;
    if (idx >= total) return;
    int c = idx % PAD;
    int r = (idx / PAD) % PAD;
    int b = idx / (PAD * PAD);
    const float* img = imgs + (size_t)b * RES * RES;

    // normal orientation
    {
        float v00 = getP(img, r,     c);
        float v10 = getP(img, r + 1, c);
        float v01 = getP(img, r,     c + 1);
        float v11 = getP(img, r + 1, c + 1);
        __half2 lo = __halves2half2(__float2half_rn(v00), __float2half_rn(v10));
        __half2 hi = __halves2half2(__float2half_rn(v01), __float2half_rn(v11));
        uint2 q;
        q.x = *reinterpret_cast<unsigned int*>(&lo);
        q.y = *reinterpret_cast<unsigned int*>(&hi);
        Q[idx] = q;
    }
    // transposed orientation: PT(r,c) = P(c,r)
    {
        float v00 = getP(img, c,     r);
        float v10 = getP(img, c,     r + 1);
        float v01 = getP(img, c + 1, r);
        float v11 = getP(img, c + 1, r + 1);
        __half2 lo = __halves2half2(__float2half_rn(v00), __float2half_rn(v10));
        __half2 hi = __halves2half2(__float2half_rn(v01), __float2half_rn(v11));
        uint2 q;
        q.x = *reinterpret_cast<unsigned int*>(&lo);
        q.y = *reinterpret_cast<unsigned int*>(&hi);
        QT[idx] = q;
    }
}

__global__ __launch_bounds__(256) void radon_kernel(
        const uint2* __restrict__ Q,
        const uint2* __restrict__ QT,
        const float* __restrict__ angles,
        float* __restrict__ out) {
    const int s = threadIdx.x;          // detector bin, lanes consecutive in s
    const int a = blockIdx.x;
    const int b = blockIdx.y;

    float theta = angles[a];
    float sn, cs;
    sincosf(theta, &sn, &cs);

    const float s_c = (float)s - 127.5f;

    // Pick orientation so per-lane (Δs) movement along the contiguous dim (pc)
    // is >= 0.707 px -> compact per-wave address footprint.
    float Rs, Rt, Cs, Ct;
    const uint2* img;
    if (fabsf(cs) >= fabsf(sn)) {
        Rs = sn; Rt = cs;  Cs = cs; Ct = -sn;
        img = Q + (size_t)b * PAD * PAD;
    } else {
        Rs = cs; Rt = -sn; Cs = sn; Ct = cs;
        img = QT + (size_t)b * PAD * PAD;
    }

    const float pr0 = fmaf(s_c, Rs, 128.5f) - 127.5f * Rt;
    const float pc0 = fmaf(s_c, Cs, 128.5f) - 127.5f * Ct;

    // Clip t so padded coords stay in (0, 257): every tap in-array; trimmed
    // samples have (near-)zero bilinear weight.
    const float LO = 1e-4f, HI = 257.0f - 1e-3f;
    float tmin = 0.0f, tmax = 255.0f;
    if (fabsf(Rt) > 1e-6f) {
        float ta = (LO - pr0) / Rt, tb = (HI - pr0) / Rt;
        tmin = fmaxf(tmin, fminf(ta, tb));
        tmax = fminf(tmax, fmaxf(ta, tb));
    } else if (!(pr0 >= LO && pr0 <= HI)) {
        tmax = -1.0f;
    }
    if (fabsf(Ct) > 1e-6f) {
        float ta = (LO - pc0) / Ct, tb = (HI - pc0) / Ct;
        tmin = fmaxf(tmin, fminf(ta, tb));
        tmax = fminf(tmax, fmaxf(ta, tb));
    } else if (!(pc0 >= LO && pc0 <= HI)) {
        tmax = -1.0f;
    }

    int t0 = (int)ceilf(tmin);
    int t1 = (int)floorf(tmax);

    float acc0 = 0.0f, acc1 = 0.0f;

    auto step = [&](float tf, float& acc) {
        float pr = fmaf(tf, Rt, pr0);
        float pc = fmaf(tf, Ct, pc0);
        float fr = floorf(pr), fc = floorf(pc);
        int ir = (int)fr, ic = (int)fc;
        float wy = pr - fr, wx = pc - fc;
        uint2 q = img[ir * PAD + ic];
        __half2 lo = *reinterpret_cast<__half2*>(&q.x);   // (v00, v10)
        __half2 hi = *reinterpret_cast<__half2*>(&q.y);   // (v01, v11)
        float2 l = __half22float2(lo);
        float2 h = __half22float2(hi);
        float c0 = fmaf(wy, l.y - l.x, l.x);
        float c1 = fmaf(wy, h.y - h.x, h.x);
        acc += fmaf(wx, c1 - c0, c0);
    };

    int t = t0;
    float tf = (float)t0;
    for (; t + 1 <= t1; t += 2) {
        step(tf, acc0);
        step(tf + 1.0f, acc1);
        tf += 2.0f;
    }
    if (t <= t1) step(tf, acc0);

    out[((size_t)b * N_ANGLES + a) * RES + s] = acc0 + acc1;
}

extern "C" void kernel_launch(void* const* d_in, const int* in_sizes, int n_in,
                              void* d_out, int out_size, void* d_ws, size_t ws_size,
                              hipStream_t stream) {
    const float* imgs   = (const float*)d_in[0];
    const float* angles = (const float*)d_in[1];
    float* out = (float*)d_out;

    uint2* Q  = (uint2*)d_ws;                               // 8*258*258*8B = 4.26MB
    uint2* QT = Q + (size_t)BATCH * PAD * PAD;              // another 4.26MB

    const int prep_total = BATCH * PAD * PAD;
    prep_pack<<<(prep_total + 255) / 256, 256, 0, stream>>>(imgs, Q, QT);

    dim3 grid(N_ANGLES, BATCH);
    radon_kernel<<<grid, 256, 0, stream>>>(Q, QT, angles, out);
}

// Round 3
// 71.046 us; speedup vs baseline: 4.1575x; 2.6466x over previous
//
#include <hip/hip_runtime.h>
#include <hip/hip_fp16.h>
#include <math.h>

#define RES 256
#define PAD 258          // RES + 1-pixel zero border on each side
#define N_ANGLES 256
#define BATCH 8

// Batch-packed texture: H[r][c] = 8 x fp16 = {img_b(r-1,c-1)}_{b=0..7}  (16B/pixel)
// Q = normal orientation, QT = transposed (texture (r,c) samples img(c-1,r-1)).
// One 16B load -> one bilinear tap for ALL 8 batch images.
__global__ void prep_pack(const float* __restrict__ imgs,
                          unsigned int* __restrict__ Qw,
                          unsigned int* __restrict__ QTw) {
    int idx = blockIdx.x * blockDim.x + threadIdx.x;
    const int total = 2 * PAD * PAD * 4;     // orient x pixel x batch-pair
    if (idx >= total) return;
    int pair   = idx & 3;
    int px     = (idx >> 2) % (PAD * PAD);
    int orient = (idx >> 2) / (PAD * PAD);
    int c = px % PAD, r = px / PAD;
    int rr = orient ? c : r;                 // image row + 1
    int cc = orient ? r : c;                 // image col + 1
    unsigned ri = (unsigned)(rr - 1), ci = (unsigned)(cc - 1);
    float v0 = 0.0f, v1 = 0.0f;
    if (ri < RES && ci < RES) {
        const float* p = imgs + ((size_t)(pair * 2) * RES + ri) * RES + ci;
        v0 = p[0];
        v1 = p[RES * RES];
    }
    __half2 h = __halves2half2(__float2half_rn(v0), __float2half_rn(v1));
    unsigned int* dst = orient ? QTw : Qw;
    dst[px * 4 + pair] = *reinterpret_cast<unsigned int*>(&h);
}

// Lane layout: wave = 16 s-positions x 4 taps. Each tap-lane loads ONE 16B
// batch-packed pixel per ray step, applies its bilinear weight, accumulates
// 8 f32 partials; shfl_xor(1)+shfl_xor(2) combines the 4 taps at the end.
__global__ __launch_bounds__(256) void radon_kernel(
        const uint4* __restrict__ Q,
        const uint4* __restrict__ QT,
        const float* __restrict__ angles,
        float* __restrict__ out) {
    const int tap = threadIdx.x & 3;
    const int s   = blockIdx.y * 64 + (threadIdx.x >> 2);
    const int a   = blockIdx.x;

    float theta = angles[a];
    float sn, cs;
    sincosf(theta, &sn, &cs);

    const float s_c = (float)s - 127.5f;

    // Orientation: keep per-lane-group column motion (|Cs|) >= 0.707.
    float Rs, Rt, Cs, Ct;
    const uint4* img;
    if (fabsf(cs) >= fabsf(sn)) {
        Rs = sn; Rt = cs;  Cs = cs; Ct = -sn;
        img = Q;
    } else {
        Rs = cs; Rt = -sn; Cs = sn; Ct = cs;
        img = QT;
    }

    const float pr0 = fmaf(s_c, Rs, 128.5f) - 127.5f * Rt;
    const float pc0 = fmaf(s_c, Cs, 128.5f) - 127.5f * Ct;

    // Clip t so padded coords stay in (0,257): every tap in-array; trimmed
    // samples have (near-)zero bilinear weight. Same result for all 4 taps.
    const float LO = 1e-4f, HI = 257.0f - 1e-3f;
    float tmin = 0.0f, tmax = 255.0f;
    if (fabsf(Rt) > 1e-6f) {
        float ta = (LO - pr0) / Rt, tb = (HI - pr0) / Rt;
        tmin = fmaxf(tmin, fminf(ta, tb));
        tmax = fminf(tmax, fmaxf(ta, tb));
    } else if (!(pr0 >= LO && pr0 <= HI)) {
        tmax = -1.0f;
    }
    if (fabsf(Ct) > 1e-6f) {
        float ta = (LO - pc0) / Ct, tb = (HI - pc0) / Ct;
        tmin = fmaxf(tmin, fminf(ta, tb));
        tmax = fminf(tmax, fmaxf(ta, tb));
    } else if (!(pc0 >= LO && pc0 <= HI)) {
        tmax = -1.0f;
    }

    const int t0 = (int)ceilf(tmin);
    const int t1 = (int)floorf(tmax);

    // Per-tap constants: pointer offset + weight affine coeffs.
    const int dr = tap >> 1, dc = tap & 1;
    const uint4* tp = img + dr * PAD + dc;
    const float xb = dc ? 0.0f : 1.0f, xs = dc ? 1.0f : -1.0f;  // w_x = xb + xs*wx
    const float yb = dr ? 0.0f : 1.0f, ys = dr ? 1.0f : -1.0f;  // w_y = yb + ys*wy

    float acc0 = 0.f, acc1 = 0.f, acc2 = 0.f, acc3 = 0.f;
    float acc4 = 0.f, acc5 = 0.f, acc6 = 0.f, acc7 = 0.f;

    float tf = (float)t0;
    #pragma unroll 2
    for (int t = t0; t <= t1; ++t) {
        float pr = fmaf(tf, Rt, pr0);
        float pc = fmaf(tf, Ct, pc0);
        tf += 1.0f;
        float fr = floorf(pr), fc = floorf(pc);
        int px = (int)fr * PAD + (int)fc;
        float w = fmaf(xs, pc - fc, xb) * fmaf(ys, pr - fr, yb);
        uint4 q = tp[px];
        float2 f;
        f = __half22float2(*reinterpret_cast<const __half2*>(&q.x));
        acc0 = fmaf(w, f.x, acc0); acc1 = fmaf(w, f.y, acc1);
        f = __half22float2(*reinterpret_cast<const __half2*>(&q.y));
        acc2 = fmaf(w, f.x, acc2); acc3 = fmaf(w, f.y, acc3);
        f = __half22float2(*reinterpret_cast<const __half2*>(&q.z));
        acc4 = fmaf(w, f.x, acc4); acc5 = fmaf(w, f.y, acc5);
        f = __half22float2(*reinterpret_cast<const __half2*>(&q.w));
        acc6 = fmaf(w, f.x, acc6); acc7 = fmaf(w, f.y, acc7);
    }

    // Combine the 4 tap lanes (lane bits 0-1).
    #define RED(x) { x += __shfl_xor(x, 1); x += __shfl_xor(x, 2); }
    RED(acc0) RED(acc1) RED(acc2) RED(acc3)
    RED(acc4) RED(acc5) RED(acc6) RED(acc7)
    #undef RED

    if (tap == 0) {
        const size_t AR = (size_t)N_ANGLES * RES;
        size_t base = (size_t)a * RES + s;
        out[base         ] = acc0;
        out[base + 1 * AR] = acc1;
        out[base + 2 * AR] = acc2;
        out[base + 3 * AR] = acc3;
        out[base + 4 * AR] = acc4;
        out[base + 5 * AR] = acc5;
        out[base + 6 * AR] = acc6;
        out[base + 7 * AR] = acc7;
    }
}

extern "C" void kernel_launch(void* const* d_in, const int* in_sizes, int n_in,
                              void* d_out, int out_size, void* d_ws, size_t ws_size,
                              hipStream_t stream) {
    const float* imgs   = (const float*)d_in[0];
    const float* angles = (const float*)d_in[1];
    float* out = (float*)d_out;

    uint4* Q  = (uint4*)d_ws;                       // PAD*PAD * 16B = 1.07MB
    uint4* QT = Q + (size_t)PAD * PAD;              // + 1.07MB

    const int prep_total = 2 * PAD * PAD * 4;
    prep_pack<<<(prep_total + 255) / 256, 256, 0, stream>>>(
        imgs, (unsigned int*)Q, (unsigned int*)QT);

    dim3 grid(N_ANGLES, 4);                         // (angle, s-quad) x 256 thr
    radon_kernel<<<grid, 256, 0, stream>>>(Q, QT, angles, out);
}

// Round 5
// 57.364 us; speedup vs baseline: 5.1491x; 1.2385x over previous
//
#include <hip/hip_runtime.h>
#include <hip/hip_fp16.h>
#include <math.h>

#define RES 256
#define TPAD 364          // padded texture dim: image rows -53..310 per axis
#define N_ANGLES 256
#define BATCH 8

// Batch-packed padded texture: T[r][c] = 8 x fp16 = {img_b(r-53, c-53)}_{b=0..7}
// (16B/pixel). Covers the entire rotated sample lattice -> NO per-step bounds
// checks needed; outside-image samples read exact zeros (= cval=0 bilinear).
// Q = normal orientation, QT = transposed.
__global__ void prep_pack(const float* __restrict__ imgs,
                          unsigned int* __restrict__ Qw,
                          unsigned int* __restrict__ QTw) {
    int idx = blockIdx.x * blockDim.x + threadIdx.x;
    const int total = 2 * TPAD * TPAD * 4;   // orient x pixel x batch-pair
    if (idx >= total) return;
    int pair   = idx & 3;
    int px     = (idx >> 2) % (TPAD * TPAD);
    int orient = (idx >> 2) / (TPAD * TPAD);
    int c = px % TPAD, r = px / TPAD;
    int rr = orient ? c : r;
    int cc = orient ? r : c;
    unsigned ri = (unsigned)(rr - 53), ci = (unsigned)(cc - 53);
    float v0 = 0.0f, v1 = 0.0f;
    if (ri < RES && ci < RES) {
        const float* p = imgs + ((size_t)(pair * 2) * RES + ri) * RES + ci;
        v0 = p[0];
        v1 = p[RES * RES];
    }
    __half2 h = __halves2half2(__float2half_rn(v0), __float2half_rn(v1));
    (orient ? QTw : Qw)[px * 4 + pair] = *reinterpret_cast<unsigned int*>(&h);
}

// Lane layout within a wave: tap(2b) | t-parity(1b) | s(3b)  -> 8 s per wave.
// grid = (angle, s-block of 32, t-half). Each lane: up to 64 strided-2 t steps,
// fp16 packed accumulation (v_pk_fma_f16), f32 flush every 16 steps.
__global__ __launch_bounds__(256) void radon_kernel(
        const uint4* __restrict__ Q,
        const uint4* __restrict__ QT,
        const float* __restrict__ angles,
        float* __restrict__ part) {
    const int tap  = threadIdx.x & 3;
    const int tpar = (threadIdx.x >> 2) & 1;
    const int s    = blockIdx.y * 32 + (threadIdx.x >> 3);
    const int a    = blockIdx.x;
    const int z    = blockIdx.z;

    float theta = angles[a];
    float sn, cs;
    sincosf(theta, &sn, &cs);

    // Orientation: per-lane column motion along contiguous dim >= 0.707 px.
    float Rs, Rt, Cs, Ct;
    const uint4* img;
    if (fabsf(cs) >= fabsf(sn)) {
        Rs = sn; Rt = cs;  Cs = cs; Ct = -sn;
        img = Q;
    } else {
        Rs = cs; Rt = -sn; Cs = sn; Ct = cs;
        img = QT;
    }

    const float s_c = (float)s - 127.5f;
    // padded coords: ppr(t) = s_c*Rs + (t-127.5)*Rt + 127.5 + 53
    const float pr0 = fmaf(s_c, Rs, 180.5f) - 127.5f * Rt;
    const float pc0 = fmaf(s_c, Cs, 180.5f) - 127.5f * Ct;

    // Work-skip clip (not address clip): nonzero bilinear only for padded
    // coords in [52, 309]. |Rt| >= 0.707 always; |Ct| may be ~0.
    const float LO = 52.0f, HI = 309.0f;
    float tmin = 0.0f, tmax = 255.0f;
    {
        float inv = 1.0f / Rt;
        float ta = (LO - pr0) * inv, tb = (HI - pr0) * inv;
        tmin = fmaxf(tmin, fminf(ta, tb));
        tmax = fminf(tmax, fmaxf(ta, tb));
    }
    if (fabsf(Ct) > 1e-6f) {
        float inv = 1.0f / Ct;
        float ta = (LO - pc0) * inv, tb = (HI - pc0) * inv;
        tmin = fmaxf(tmin, fminf(ta, tb));
        tmax = fminf(tmax, fmaxf(ta, tb));
    } else if (!(pc0 >= LO && pc0 <= HI)) {
        tmax = -1.0f;
    }

    // This lane covers t = zb + tpar + 2*i, i in [0,64). Chunk i by 16.
    const float zb = (float)(z * 128);
    const float tb0 = zb + (float)tpar;
    int i0 = (int)ceilf((tmin - tb0) * 0.5f);
    int i1 = (int)floorf((tmax - tb0) * 0.5f);
    i0 = max(i0, 0);
    i1 = min(i1, 63);
    int c0 = i0 >> 4, c1 = i1 >> 4;           // c1 < c0 when no work
    if (i1 < i0) { c0 = 1; c1 = 0; }

    // Per-tap constants: pointer offset + weight affine coeffs.
    const int dr = tap >> 1, dc = tap & 1;
    const uint4* tp = img + dr * TPAD + dc;
    const float xb = dc ? 0.0f : 1.0f, xs = dc ? 1.0f : -1.0f;  // wx-weight
    const float yb = dr ? 0.0f : 1.0f, ys = dr ? 1.0f : -1.0f;  // wy-weight

    float a0 = 0.f, a1 = 0.f, a2 = 0.f, a3 = 0.f;
    float a4 = 0.f, a5 = 0.f, a6 = 0.f, a7 = 0.f;

    for (int c = c0; c <= c1; ++c) {
        __half2 h0 = __halves2half2(__ushort_as_half(0), __ushort_as_half(0));
        __half2 h1 = h0, h2 = h0, h3 = h0;
        float tf = fmaf(32.0f, (float)c, tb0);
        #pragma unroll
        for (int k = 0; k < 16; ++k) {
            float ppr = fmaf(tf, Rt, pr0);
            float ppc = fmaf(tf, Ct, pc0);
            tf += 2.0f;
            float fr = floorf(ppr), fc = floorf(ppc);
            int ipx = (int)fr * TPAD + (int)fc;
            float w = fmaf(xs, ppc - fc, xb) * fmaf(ys, ppr - fr, yb);
            auto whr = __builtin_amdgcn_cvt_pkrtz(w, w);   // __fp16 x2 vector
            __half2 wh = *reinterpret_cast<__half2*>(&whr);
            uint4 q = tp[ipx];
            h0 = __hfma2(wh, *reinterpret_cast<const __half2*>(&q.x), h0);
            h1 = __hfma2(wh, *reinterpret_cast<const __half2*>(&q.y), h1);
            h2 = __hfma2(wh, *reinterpret_cast<const __half2*>(&q.z), h2);
            h3 = __hfma2(wh, *reinterpret_cast<const __half2*>(&q.w), h3);
        }
        float2 f;
        f = __half22float2(h0); a0 += f.x; a1 += f.y;
        f = __half22float2(h1); a2 += f.x; a3 += f.y;
        f = __half22float2(h2); a4 += f.x; a5 += f.y;
        f = __half22float2(h3); a6 += f.x; a7 += f.y;
    }

    // Combine tap lanes (bits 0-1) and t-parity lanes (bit 2).
    #define RED(x) { x += __shfl_xor(x, 1); x += __shfl_xor(x, 2); x += __shfl_xor(x, 4); }
    RED(a0) RED(a1) RED(a2) RED(a3)
    RED(a4) RED(a5) RED(a6) RED(a7)
    #undef RED

    if ((threadIdx.x & 7) == 0) {
        const size_t AR = (size_t)N_ANGLES * RES;
        size_t base = ((size_t)z * BATCH) * AR + (size_t)a * RES + s;
        part[base         ] = a0;
        part[base + 1 * AR] = a1;
        part[base + 2 * AR] = a2;
        part[base + 3 * AR] = a3;
        part[base + 4 * AR] = a4;
        part[base + 5 * AR] = a5;
        part[base + 6 * AR] = a6;
        part[base + 7 * AR] = a7;
    }
}

__global__ void combine(const float4* __restrict__ p, float4* __restrict__ out) {
    const int n4 = BATCH * N_ANGLES * RES / 4;
    int i = blockIdx.x * blockDim.x + threadIdx.x;
    if (i < n4) {
        float4 x = p[i];
        float4 y = p[i + n4];
        out[i] = make_float4(x.x + y.x, x.y + y.y, x.z + y.z, x.w + y.w);
    }
}

extern "C" void kernel_launch(void* const* d_in, const int* in_sizes, int n_in,
                              void* d_out, int out_size, void* d_ws, size_t ws_size,
                              hipStream_t stream) {
    const float* imgs   = (const float*)d_in[0];
    const float* angles = (const float*)d_in[1];
    float* out = (float*)d_out;

    const size_t texN = (size_t)TPAD * TPAD;            // pixels per orientation
    uint4* Q    = (uint4*)d_ws;                         // texN*16B = 2.12MB
    uint4* QT   = Q + texN;                             // + 2.12MB
    float* part = (float*)(QT + texN);                  // 2 * 2MB partials

    const int prep_total = 2 * TPAD * TPAD * 4;
    prep_pack<<<(prep_total + 255) / 256, 256, 0, stream>>>(
        imgs, (unsigned int*)Q, (unsigned int*)QT);

    dim3 grid(N_ANGLES, 8, 2);                          // 4096 blocks x 256 thr
    radon_kernel<<<grid, 256, 0, stream>>>(Q, QT, angles, part);

    const int n4 = BATCH * N_ANGLES * RES / 4;
    combine<<<(n4 + 255) / 256, 256, 0, stream>>>((const float4*)part, (float4*)out);
}